// Round 11
// baseline (67.581 us; speedup 1.0000x reference)
//
#include <hip/hip_runtime.h>
#include <hip/hip_bf16.h>
#include <stdint.h>

#define N_TOT 8192
#define BSZ   4096
#define NCH   32                     // 8192/256 column groups
#define SCALE2 28.853900817779268f   // 20 * log2(e): base-2 domain

typedef _Float16 f16x8 __attribute__((ext_vector_type(8)));
typedef float f32x4 __attribute__((ext_vector_type(4)));

extern "C" __device__ float __ocml_native_exp2_f32(float);   // -> v_exp_f32
#define EXP2(x) __ocml_native_exp2_f32(x)

// ---------------- prep: f32 -> fp16 in FRAGMENT-TILE layout ----------------
// H2 byte addr = rowblk*4096 + k8*256 + (r&15)*16  (rowblk=r>>4, k8=k/8)
// => every MFMA fragment load (16 rows x 8 k's) is a contiguous 1KB wave load.
__global__ __launch_bounds__(256) void prep_kernel(
    const float* __restrict__ feat, const int* __restrict__ labels,
    _Float16* __restrict__ H2, unsigned char* __restrict__ lab8, int* __restrict__ cnt) {
  if (blockIdx.x == 512) {   // label histogram + byte labels
    __shared__ int h[128];
    if (threadIdx.x < 128) h[threadIdx.x] = 0;
    __syncthreads();
    for (int i = threadIdx.x; i < BSZ; i += 256) atomicAdd(&h[labels[i] & 127], 1);
    __syncthreads();
    if (threadIdx.x < 128) cnt[threadIdx.x] = h[threadIdx.x];
    for (int i = threadIdx.x; i < N_TOT; i += 256)
      lab8[i] = (unsigned char)labels[i & (BSZ - 1)];
    return;
  }
  int idx = blockIdx.x * 256 + threadIdx.x;   // 131072
  int rowblk = idx >> 8, inner = idx & 255;
  int k8 = inner >> 4, rlo = inner & 15;
  int r = rowblk * 16 + rlo;
  int b = r & (BSZ - 1), v = r >> 12;         // cf row r = features[b, v, :]
  const float* src = feat + ((size_t)((b << 1) + v) << 7) + k8 * 8;
  float4 x0 = *(const float4*)src;
  float4 x1 = *(const float4*)(src + 4);
  float xs[8] = {x0.x, x0.y, x0.z, x0.w, x1.x, x1.y, x1.z, x1.w};
  f16x8 hv;
#pragma unroll
  for (int j = 0; j < 8; ++j) hv[j] = (_Float16)xs[j];
  *(f16x8*)((char*)H2 + (size_t)idx * 16) = hv;
}

// ---------------- LDS-free strip GEMM: wave = 32 rows x 256 cols, K=128 ----------------
// 4-wave blocks share one cg (B tiles hit L1). All fragment loads are coalesced
// 1KB wave loads from the tiled H2 layout. Transposed MFMA:
//   acc[m][ni][r] = C[row = strip*32+m*16+lr16][col = cg*256+t*64+ni*16+lq*4+r]
// Per-lane online (max, exp2-sum) over the lane's own 16 cols per m -- NO cross-lane
// ops inside the loop (the old shfl/__any chains were the latency wall). Lane (M,S)
// pairs are max-merged across lq once at the end; any normalizer M is exact since
// partials are carried as (M, S=sum exp2(v-M)).
__global__ __launch_bounds__(256, 4) void gemm_kernel(
    const _Float16* __restrict__ H2, const int* __restrict__ labels,
    const unsigned char* __restrict__ lab8,
    float* __restrict__ pM, float* __restrict__ pS) {
  int orig = blockIdx.x;                 // 2048 blocks
  int xcd = orig & 7, j = orig >> 3;     // dispatch round-robins XCDs (perf-only)
  int cg = xcd * 4 + (j & 3);            // [0,32): 4 col-groups pinned per XCD
  int sp = j >> 2;                       // [0,64): strip-quad
  int wave = threadIdx.x >> 6, lane = threadIdx.x & 63;
  int strip = sp * 4 + wave;             // [0,256): 32-row strip
  int lq = lane >> 4, lr16 = lane & 15;

  const uint32_t rowbase = (uint32_t)strip * 32;
  const char* Hb = (const char*)H2;
  const uint32_t laneoff = lq * 256 + lr16 * 16;   // lane's byte offset within a 1KB frag

  int lrw[2];
#pragma unroll
  for (int m = 0; m < 2; ++m)
    lrw[m] = labels[(rowbase + m * 16 + lr16) & (BSZ - 1)];

  // ---- A fragments (8 coalesced 1KB loads), pre-scaled ----
  f16x8 Areg[2][4];
#pragma unroll
  for (int m = 0; m < 2; ++m)
#pragma unroll
    for (int kb = 0; kb < 4; ++kb)
      Areg[m][kb] = *(const f16x8*)(Hb + (size_t)((rowbase >> 4) + m) * 4096 + kb * 1024 + laneoff);
#pragma unroll
  for (int m = 0; m < 2; ++m)
#pragma unroll
    for (int kb = 0; kb < 4; ++kb)
      Areg[m][kb] = Areg[m][kb] * (_Float16)SCALE2;

  const char* Bbase = Hb + (size_t)cg * 65536;     // cg*16 colblks * 4096B

#define BLOAD(T, NI, KB) \
  (*(const f16x8*)(Bbase + ((T) * 4 + (NI)) * 4096 + (KB) * 1024 + laneoff))

  f32x4 acc[2][4];
  float mxv[2] = {-3.0e38f, -3.0e38f}, sv[2] = {0.0f, 0.0f};

  f16x8 Bb[2][4];
#pragma unroll
  for (int ni = 0; ni < 4; ++ni) Bb[0][ni] = BLOAD(0, ni, 0);

#pragma unroll
  for (int t = 0; t < 4; ++t) {
#pragma unroll
    for (int m = 0; m < 2; ++m)
#pragma unroll
      for (int ni = 0; ni < 4; ++ni) acc[m][ni] = f32x4{0.f, 0.f, 0.f, 0.f};
    uint32_t labw[4];
#pragma unroll
    for (int ni = 0; ni < 4; ++ni)
      labw[ni] = *(const uint32_t*)(lab8 + cg * 256 + t * 64 + ni * 16 + lq * 4);

#pragma unroll
    for (int kb = 0; kb < 4; ++kb) {
      int cur = kb & 1;
      if (kb < 3) {
#pragma unroll
        for (int ni = 0; ni < 4; ++ni) Bb[cur ^ 1][ni] = BLOAD(t, ni, kb + 1);
      } else if (t < 3) {
#pragma unroll
        for (int ni = 0; ni < 4; ++ni) Bb[cur ^ 1][ni] = BLOAD(t + 1, ni, 0);
      }
      __builtin_amdgcn_s_setprio(1);
#pragma unroll
      for (int m = 0; m < 2; ++m)
#pragma unroll
        for (int ni = 0; ni < 4; ++ni)
          acc[m][ni] = __builtin_amdgcn_mfma_f32_16x16x32_f16(Bb[cur][ni], Areg[m][kb], acc[m][ni], 0, 0, 0);
      __builtin_amdgcn_s_setprio(0);
    }

    // ---- per-lane epilogue: mask in place, lane-local online (max, exp2-sum) ----
#pragma unroll
    for (int m = 0; m < 2; ++m) {
#pragma unroll
      for (int ni = 0; ni < 4; ++ni)
#pragma unroll
        for (int r = 0; r < 4; ++r) {
          int lc = (labw[ni] >> (8 * r)) & 255;
          acc[m][ni][r] = (lrw[m] != lc) ? acc[m][ni][r] : 0.0f;
        }
      float b0 = fmaxf(fmaxf(acc[m][0][0], acc[m][0][1]), fmaxf(acc[m][0][2], acc[m][0][3]));
      float b1 = fmaxf(fmaxf(acc[m][1][0], acc[m][1][1]), fmaxf(acc[m][1][2], acc[m][1][3]));
      float b2 = fmaxf(fmaxf(acc[m][2][0], acc[m][2][1]), fmaxf(acc[m][2][2], acc[m][2][3]));
      float b3 = fmaxf(fmaxf(acc[m][3][0], acc[m][3][1]), fmaxf(acc[m][3][2], acc[m][3][3]));
      float bm = fmaxf(fmaxf(b0, b1), fmaxf(b2, b3));
      float nm = fmaxf(mxv[m], bm);
      float s0 = 0.f, s1 = 0.f, s2 = 0.f, s3 = 0.f;
#pragma unroll
      for (int r = 0; r < 4; ++r) {
        s0 += EXP2(acc[m][0][r] - nm);
        s1 += EXP2(acc[m][1][r] - nm);
        s2 += EXP2(acc[m][2][r] - nm);
        s3 += EXP2(acc[m][3][r] - nm);
      }
      sv[m] = sv[m] * EXP2(mxv[m] - nm) + ((s0 + s1) + (s2 + s3));
      mxv[m] = nm;
    }
  }
#undef BLOAD

  // ---- merge (M,S) across the 4 lq lane-groups (exact max-merge), write partials ----
#pragma unroll
  for (int m = 0; m < 2; ++m) {
    float M = mxv[m], S = sv[m];
#pragma unroll
    for (int off = 16; off < 64; off <<= 1) {
      float Mo = __shfl_xor(M, off, 64);
      float So = __shfl_xor(S, off, 64);
      float Mn = fmaxf(M, Mo);
      S = S * EXP2(M - Mn) + So * EXP2(Mo - Mn);
      M = Mn;
    }
    if (lane < 16) {
      pM[(size_t)cg * N_TOT + rowbase + m * 16 + lane] = M;
      pS[(size_t)cg * N_TOT + rowbase + m * 16 + lane] = S;
    }
  }
}

// ---------------- combine 32 chunk-partials per row, partial-sum S per block ----------------
__global__ __launch_bounds__(256) void rowred_kernel(const float* __restrict__ pM,
                                                     const float* __restrict__ pS,
                                                     float* __restrict__ blockS) {
  int row = blockIdx.x * 256 + threadIdx.x;   // 32 blocks x 256 = 8192 rows
  float M = -3.0e38f;
#pragma unroll
  for (int c = 0; c < NCH; ++c) M = fmaxf(M, pM[(size_t)c * N_TOT + row]);
  float s = 0.0f;
#pragma unroll
  for (int c = 0; c < NCH; ++c)
    s += pS[(size_t)c * N_TOT + row] * EXP2(pM[(size_t)c * N_TOT + row] - M);
  __shared__ float red[256];
  red[threadIdx.x] = s;
  __syncthreads();
  for (int st = 128; st > 0; st >>= 1) {
    if (threadIdx.x < st) red[threadIdx.x] += red[threadIdx.x + st];
    __syncthreads();
  }
  if (threadIdx.x == 0) blockS[blockIdx.x] = red[0];
}

// ---------------- final scalar: S, N, validity -> loss ----------------
__global__ void final_kernel(const float* __restrict__ blockS, const int* __restrict__ cnt,
                             float* __restrict__ out) {
  int lane = threadIdx.x;              // 1 wave
  float s = (lane < 32) ? blockS[lane] : 0.0f;
#pragma unroll
  for (int off = 1; off < 64; off <<= 1) s += __shfl_xor(s, off, 64);
  if (lane == 0) {
    double Stot = (double)s;
    long long sumsq = 0;
    int nval = 0;
    for (int c = 0; c < 128; ++c) {
      long long cc = cnt[c];
      sumsq += cc * cc;
      if (cc > 0 && cc < BSZ) nval += 2 * (int)cc;   // valid rows iff not all labels equal
    }
    double Nd = (double)N_TOT * (double)N_TOT - 4.0 * (double)sumsq;
    float loss;
    if (Nd <= 0.0 || nval == 0) {
      loss = logf(1e-6f);              // all_zero branch: xv stays 0 -> log(eps)
    } else {
      float x = (float)(Stot / Nd);
      loss = ((float)nval * logf(x + 1e-6f) +
              (float)(N_TOT - nval) * logf(1e-6f)) / (float)N_TOT;
    }
    out[0] = loss;
  }
}

extern "C" void kernel_launch(void* const* d_in, const int* in_sizes, int n_in,
                              void* d_out, int out_size, void* d_ws, size_t ws_size,
                              hipStream_t stream) {
  const float* feat = (const float*)d_in[0];
  const int* labels = (const int*)d_in[1];
  float* out = (float*)d_out;

  char* ws = (char*)d_ws;
  _Float16* H2        = (_Float16*)(ws);                 // 8192*128*2 = 2,097,152 (tiled layout)
  unsigned char* lab8 = (unsigned char*)(ws + 2097152);  // 8,192
  float* pM           = (float*)(ws + 2105344);          // 32*8192*4 = 1,048,576
  float* pS           = (float*)(ws + 3153920);          // 1,048,576
  int* cnt            = (int*)(ws + 4202496);            // 512
  float* blockS       = (float*)(ws + 4203008);          // 128

  prep_kernel<<<513, 256, 0, stream>>>(feat, labels, H2, lab8, cnt);
  gemm_kernel<<<2048, 256, 0, stream>>>(H2, labels, lab8, pM, pS);
  rowred_kernel<<<32, 256, 0, stream>>>(pM, pS, blockS);
  final_kernel<<<1, 64, 0, stream>>>(blockS, cnt, out);
}

// Round 12
// 67.341 us; speedup vs baseline: 1.0036x; 1.0036x over previous
//
#include <hip/hip_runtime.h>
#include <hip/hip_bf16.h>
#include <stdint.h>

#define N_TOT 8192
#define BSZ   4096
#define NCH   32                     // 8192/256 column groups
#define SCALE2 28.853900817779268f   // 20 * log2(e): base-2 domain

typedef _Float16 f16x8 __attribute__((ext_vector_type(8)));
typedef float f32x4 __attribute__((ext_vector_type(4)));

// Native 2^x: MUST lower to a bare v_exp_f32, never a function call
// (an OCML extern decl compiled to a real call in R11: ABI 64v/32s regs +
//  90 MB of caller-save spill traffic per dispatch).
__device__ __forceinline__ float fast_exp2(float x) {
#if __has_builtin(__builtin_amdgcn_exp2f)
  return __builtin_amdgcn_exp2f(x);
#else
  float r;
  asm volatile("v_exp_f32 %0, %1\n\ts_nop 1" : "=v"(r) : "v"(x));
  return r;
#endif
}
#define EXP2(x) fast_exp2(x)

// ---------------- prep: f32 -> fp16 in FRAGMENT-TILE layout ----------------
// H2 byte addr = rowblk*4096 + k8*256 + (r&15)*16  (rowblk=r>>4, k8=k/8)
// => every MFMA fragment load (16 rows x 8 k's) is a contiguous 1KB wave load.
__global__ __launch_bounds__(256) void prep_kernel(
    const float* __restrict__ feat, const int* __restrict__ labels,
    _Float16* __restrict__ H2, unsigned char* __restrict__ lab8, int* __restrict__ cnt) {
  if (blockIdx.x == 512) {   // label histogram + byte labels
    __shared__ int h[128];
    if (threadIdx.x < 128) h[threadIdx.x] = 0;
    __syncthreads();
    for (int i = threadIdx.x; i < BSZ; i += 256) atomicAdd(&h[labels[i] & 127], 1);
    __syncthreads();
    if (threadIdx.x < 128) cnt[threadIdx.x] = h[threadIdx.x];
    for (int i = threadIdx.x; i < N_TOT; i += 256)
      lab8[i] = (unsigned char)labels[i & (BSZ - 1)];
    return;
  }
  int idx = blockIdx.x * 256 + threadIdx.x;   // 131072
  int rowblk = idx >> 8, inner = idx & 255;
  int k8 = inner >> 4, rlo = inner & 15;
  int r = rowblk * 16 + rlo;
  int b = r & (BSZ - 1), v = r >> 12;         // cf row r = features[b, v, :]
  const float* src = feat + ((size_t)((b << 1) + v) << 7) + k8 * 8;
  float4 x0 = *(const float4*)src;
  float4 x1 = *(const float4*)(src + 4);
  float xs[8] = {x0.x, x0.y, x0.z, x0.w, x1.x, x1.y, x1.z, x1.w};
  f16x8 hv;
#pragma unroll
  for (int j = 0; j < 8; ++j) hv[j] = (_Float16)xs[j];
  *(f16x8*)((char*)H2 + (size_t)idx * 16) = hv;
}

// ---------------- LDS-free strip GEMM: wave = 32 rows x 256 cols, K=128 ----------------
// 4-wave blocks share one cg (B tiles hit L1). All fragment loads are coalesced
// 1KB wave loads from the tiled H2 layout. Transposed MFMA:
//   acc[m][ni][r] = C[row = strip*32+m*16+lr16][col = cg*256+t*64+ni*16+lq*4+r]
// Per-lane online (max, exp2-sum) over the lane's own 16 cols per m -- no cross-lane
// ops inside the loop. Lane (M,S) pairs are max-merged across lq once at the end.
__global__ __launch_bounds__(256, 4) void gemm_kernel(
    const _Float16* __restrict__ H2, const int* __restrict__ labels,
    const unsigned char* __restrict__ lab8,
    float* __restrict__ pM, float* __restrict__ pS) {
  int orig = blockIdx.x;                 // 2048 blocks
  int xcd = orig & 7, j = orig >> 3;     // dispatch round-robins XCDs (perf-only)
  int cg = xcd * 4 + (j & 3);            // [0,32): 4 col-groups pinned per XCD
  int sp = j >> 2;                       // [0,64): strip-quad
  int wave = threadIdx.x >> 6, lane = threadIdx.x & 63;
  int strip = sp * 4 + wave;             // [0,256): 32-row strip
  int lq = lane >> 4, lr16 = lane & 15;

  const uint32_t rowbase = (uint32_t)strip * 32;
  const char* Hb = (const char*)H2;
  const uint32_t laneoff = lq * 256 + lr16 * 16;   // lane's byte offset within a 1KB frag

  int lrw[2];
#pragma unroll
  for (int m = 0; m < 2; ++m)
    lrw[m] = labels[(rowbase + m * 16 + lr16) & (BSZ - 1)];

  // ---- A fragments (8 coalesced 1KB loads), pre-scaled ----
  f16x8 Areg[2][4];
#pragma unroll
  for (int m = 0; m < 2; ++m)
#pragma unroll
    for (int kb = 0; kb < 4; ++kb)
      Areg[m][kb] = *(const f16x8*)(Hb + (size_t)((rowbase >> 4) + m) * 4096 + kb * 1024 + laneoff);
#pragma unroll
  for (int m = 0; m < 2; ++m)
#pragma unroll
    for (int kb = 0; kb < 4; ++kb)
      Areg[m][kb] = Areg[m][kb] * (_Float16)SCALE2;

  const char* Bbase = Hb + (size_t)cg * 65536;     // cg*16 colblks * 4096B

#define BLOAD(T, NI, KB) \
  (*(const f16x8*)(Bbase + ((T) * 4 + (NI)) * 4096 + (KB) * 1024 + laneoff))

  f32x4 acc[2][4];
  float mxv[2] = {-3.0e38f, -3.0e38f}, sv[2] = {0.0f, 0.0f};

  f16x8 Bb[2][4];
#pragma unroll
  for (int ni = 0; ni < 4; ++ni) Bb[0][ni] = BLOAD(0, ni, 0);

#pragma unroll
  for (int t = 0; t < 4; ++t) {
#pragma unroll
    for (int m = 0; m < 2; ++m)
#pragma unroll
      for (int ni = 0; ni < 4; ++ni) acc[m][ni] = f32x4{0.f, 0.f, 0.f, 0.f};
    uint32_t labw[4];
#pragma unroll
    for (int ni = 0; ni < 4; ++ni)
      labw[ni] = *(const uint32_t*)(lab8 + cg * 256 + t * 64 + ni * 16 + lq * 4);

#pragma unroll
    for (int kb = 0; kb < 4; ++kb) {
      int cur = kb & 1;
      if (kb < 3) {
#pragma unroll
        for (int ni = 0; ni < 4; ++ni) Bb[cur ^ 1][ni] = BLOAD(t, ni, kb + 1);
      } else if (t < 3) {
#pragma unroll
        for (int ni = 0; ni < 4; ++ni) Bb[cur ^ 1][ni] = BLOAD(t + 1, ni, 0);
      }
      __builtin_amdgcn_s_setprio(1);
#pragma unroll
      for (int m = 0; m < 2; ++m)
#pragma unroll
        for (int ni = 0; ni < 4; ++ni)
          acc[m][ni] = __builtin_amdgcn_mfma_f32_16x16x32_f16(Bb[cur][ni], Areg[m][kb], acc[m][ni], 0, 0, 0);
      __builtin_amdgcn_s_setprio(0);
    }

    // ---- per-lane epilogue: mask in place, lane-local online (max, exp2-sum) ----
#pragma unroll
    for (int m = 0; m < 2; ++m) {
#pragma unroll
      for (int ni = 0; ni < 4; ++ni)
#pragma unroll
        for (int r = 0; r < 4; ++r) {
          int lc = (labw[ni] >> (8 * r)) & 255;
          acc[m][ni][r] = (lrw[m] != lc) ? acc[m][ni][r] : 0.0f;
        }
      float b0 = fmaxf(fmaxf(acc[m][0][0], acc[m][0][1]), fmaxf(acc[m][0][2], acc[m][0][3]));
      float b1 = fmaxf(fmaxf(acc[m][1][0], acc[m][1][1]), fmaxf(acc[m][1][2], acc[m][1][3]));
      float b2 = fmaxf(fmaxf(acc[m][2][0], acc[m][2][1]), fmaxf(acc[m][2][2], acc[m][2][3]));
      float b3 = fmaxf(fmaxf(acc[m][3][0], acc[m][3][1]), fmaxf(acc[m][3][2], acc[m][3][3]));
      float bm = fmaxf(fmaxf(b0, b1), fmaxf(b2, b3));
      float nm = fmaxf(mxv[m], bm);
      float s0 = 0.f, s1 = 0.f, s2 = 0.f, s3 = 0.f;
#pragma unroll
      for (int r = 0; r < 4; ++r) {
        s0 += EXP2(acc[m][0][r] - nm);
        s1 += EXP2(acc[m][1][r] - nm);
        s2 += EXP2(acc[m][2][r] - nm);
        s3 += EXP2(acc[m][3][r] - nm);
      }
      sv[m] = sv[m] * EXP2(mxv[m] - nm) + ((s0 + s1) + (s2 + s3));
      mxv[m] = nm;
    }
  }
#undef BLOAD

  // ---- merge (M,S) across the 4 lq lane-groups (exact max-merge), write partials ----
#pragma unroll
  for (int m = 0; m < 2; ++m) {
    float M = mxv[m], S = sv[m];
#pragma unroll
    for (int off = 16; off < 64; off <<= 1) {
      float Mo = __shfl_xor(M, off, 64);
      float So = __shfl_xor(S, off, 64);
      float Mn = fmaxf(M, Mo);
      S = S * EXP2(M - Mn) + So * EXP2(Mo - Mn);
      M = Mn;
    }
    if (lane < 16) {
      pM[(size_t)cg * N_TOT + rowbase + m * 16 + lane] = M;
      pS[(size_t)cg * N_TOT + rowbase + m * 16 + lane] = S;
    }
  }
}

// ---------------- combine 32 chunk-partials per row, partial-sum S per block ----------------
__global__ __launch_bounds__(256) void rowred_kernel(const float* __restrict__ pM,
                                                     const float* __restrict__ pS,
                                                     float* __restrict__ blockS) {
  int row = blockIdx.x * 256 + threadIdx.x;   // 32 blocks x 256 = 8192 rows
  float M = -3.0e38f;
#pragma unroll
  for (int c = 0; c < NCH; ++c) M = fmaxf(M, pM[(size_t)c * N_TOT + row]);
  float s = 0.0f;
#pragma unroll
  for (int c = 0; c < NCH; ++c)
    s += pS[(size_t)c * N_TOT + row] * EXP2(pM[(size_t)c * N_TOT + row] - M);
  __shared__ float red[256];
  red[threadIdx.x] = s;
  __syncthreads();
  for (int st = 128; st > 0; st >>= 1) {
    if (threadIdx.x < st) red[threadIdx.x] += red[threadIdx.x + st];
    __syncthreads();
  }
  if (threadIdx.x == 0) blockS[blockIdx.x] = red[0];
}

// ---------------- final scalar: S, N, validity -> loss ----------------
__global__ void final_kernel(const float* __restrict__ blockS, const int* __restrict__ cnt,
                             float* __restrict__ out) {
  int lane = threadIdx.x;              // 1 wave
  float s = (lane < 32) ? blockS[lane] : 0.0f;
#pragma unroll
  for (int off = 1; off < 64; off <<= 1) s += __shfl_xor(s, off, 64);
  if (lane == 0) {
    double Stot = (double)s;
    long long sumsq = 0;
    int nval = 0;
    for (int c = 0; c < 128; ++c) {
      long long cc = cnt[c];
      sumsq += cc * cc;
      if (cc > 0 && cc < BSZ) nval += 2 * (int)cc;   // valid rows iff not all labels equal
    }
    double Nd = (double)N_TOT * (double)N_TOT - 4.0 * (double)sumsq;
    float loss;
    if (Nd <= 0.0 || nval == 0) {
      loss = logf(1e-6f);              // all_zero branch: xv stays 0 -> log(eps)
    } else {
      float x = (float)(Stot / Nd);
      loss = ((float)nval * logf(x + 1e-6f) +
              (float)(N_TOT - nval) * logf(1e-6f)) / (float)N_TOT;
    }
    out[0] = loss;
  }
}

extern "C" void kernel_launch(void* const* d_in, const int* in_sizes, int n_in,
                              void* d_out, int out_size, void* d_ws, size_t ws_size,
                              hipStream_t stream) {
  const float* feat = (const float*)d_in[0];
  const int* labels = (const int*)d_in[1];
  float* out = (float*)d_out;

  char* ws = (char*)d_ws;
  _Float16* H2        = (_Float16*)(ws);                 // 8192*128*2 = 2,097,152 (tiled layout)
  unsigned char* lab8 = (unsigned char*)(ws + 2097152);  // 8,192
  float* pM           = (float*)(ws + 2105344);          // 32*8192*4 = 1,048,576
  float* pS           = (float*)(ws + 3153920);          // 1,048,576
  int* cnt            = (int*)(ws + 4202496);            // 512
  float* blockS       = (float*)(ws + 4203008);          // 128

  prep_kernel<<<513, 256, 0, stream>>>(feat, labels, H2, lab8, cnt);
  gemm_kernel<<<2048, 256, 0, stream>>>(H2, labels, lab8, pM, pS);
  rowred_kernel<<<32, 256, 0, stream>>>(pM, pS, blockS);
  final_kernel<<<1, 64, 0, stream>>>(blockS, cnt, out);
}

// Round 13
// 50.482 us; speedup vs baseline: 1.3387x; 1.3340x over previous
//
#include <hip/hip_runtime.h>
#include <hip/hip_bf16.h>
#include <stdint.h>

#define N_TOT 8192
#define BSZ   4096
#define NCH   32                     // 8192/256 column groups
#define SCALE2 28.853900817779268f   // 20 * log2(e): base-2 domain

typedef _Float16 f16x8 __attribute__((ext_vector_type(8)));
typedef float f32x4 __attribute__((ext_vector_type(4)));

// Native 2^x that ALWAYS inlines (no call ABI, no scratch):
__device__ __forceinline__ float fast_exp2(float x) {
#if __has_builtin(__builtin_amdgcn_exp2f)
  return __builtin_amdgcn_exp2f(x);     // bare v_exp_f32
#else
  return exp2f(x);                      // header-inline libm (no extern call)
#endif
}
#define EXP2(x) fast_exp2(x)

// ---------------- prep: f32 -> fp16 in FRAGMENT-TILE layout ----------------
// H2 byte addr = rowblk*4096 + k8*256 + (r&15)*16  (rowblk=r>>4, k8=k/8)
// => every MFMA fragment load (16 rows x 8 k's) is a contiguous 1KB wave load.
__global__ __launch_bounds__(256) void prep13_kernel(
    const float* __restrict__ feat, const int* __restrict__ labels,
    _Float16* __restrict__ H2, unsigned char* __restrict__ lab8, int* __restrict__ cnt) {
  if (blockIdx.x == 512) {   // label histogram + byte labels
    __shared__ int h[128];
    if (threadIdx.x < 128) h[threadIdx.x] = 0;
    __syncthreads();
    for (int i = threadIdx.x; i < BSZ; i += 256) atomicAdd(&h[labels[i] & 127], 1);
    __syncthreads();
    if (threadIdx.x < 128) cnt[threadIdx.x] = h[threadIdx.x];
    for (int i = threadIdx.x; i < N_TOT; i += 256)
      lab8[i] = (unsigned char)labels[i & (BSZ - 1)];
    return;
  }
  int idx = blockIdx.x * 256 + threadIdx.x;   // 131072
  int rowblk = idx >> 8, inner = idx & 255;
  int k8 = inner >> 4, rlo = inner & 15;
  int r = rowblk * 16 + rlo;
  int b = r & (BSZ - 1), v = r >> 12;         // cf row r = features[b, v, :]
  const float* src = feat + ((size_t)((b << 1) + v) << 7) + k8 * 8;
  float4 x0 = *(const float4*)src;
  float4 x1 = *(const float4*)(src + 4);
  float xs[8] = {x0.x, x0.y, x0.z, x0.w, x1.x, x1.y, x1.z, x1.w};
  f16x8 hv;
#pragma unroll
  for (int j = 0; j < 8; ++j) hv[j] = (_Float16)xs[j];
  *(f16x8*)((char*)H2 + (size_t)idx * 16) = hv;
}

// ---------------- LDS-free strip GEMM: wave = 32 rows x 256 cols, K=128 ----------------
// 4-wave blocks share one cg (B tiles hit L1). All fragment loads are coalesced
// 1KB wave loads from the tiled H2 layout. Transposed MFMA:
//   acc[m][ni][r] = C[row = strip*32+m*16+lr16][col = cg*256+t*64+ni*16+lq*4+r]
// Per-lane online (max, exp2-sum); lane (M,S) pairs max-merged across lq at the end.
// NOTE: no min-waves hint -- VGPR cap 512, allocator must not spill (R11/R12 showed
// a forced 64-VGPR + 90MB-scratch pathology under (256,4)).
__global__ __launch_bounds__(256) void gemm13_kernel(
    const _Float16* __restrict__ H2, const int* __restrict__ labels,
    const unsigned char* __restrict__ lab8,
    float* __restrict__ pM, float* __restrict__ pS) {
  int orig = blockIdx.x;                 // 2048 blocks
  int xcd = orig & 7, j = orig >> 3;     // dispatch round-robins XCDs (perf-only)
  int cg = xcd * 4 + (j & 3);            // [0,32): 4 col-groups pinned per XCD
  int sp = j >> 2;                       // [0,64): strip-quad
  int wave = threadIdx.x >> 6, lane = threadIdx.x & 63;
  int strip = sp * 4 + wave;             // [0,256): 32-row strip
  int lq = lane >> 4, lr16 = lane & 15;

  const uint32_t rowbase = (uint32_t)strip * 32;
  const char* Hb = (const char*)H2;
  const uint32_t laneoff = lq * 256 + lr16 * 16;   // lane's byte offset within a 1KB frag

  int lrw[2];
#pragma unroll
  for (int m = 0; m < 2; ++m)
    lrw[m] = labels[(rowbase + m * 16 + lr16) & (BSZ - 1)];

  // ---- A fragments (8 coalesced 1KB loads), pre-scaled ----
  f16x8 Areg[2][4];
#pragma unroll
  for (int m = 0; m < 2; ++m)
#pragma unroll
    for (int kb = 0; kb < 4; ++kb)
      Areg[m][kb] = *(const f16x8*)(Hb + (size_t)((rowbase >> 4) + m) * 4096 + kb * 1024 + laneoff);
#pragma unroll
  for (int m = 0; m < 2; ++m)
#pragma unroll
    for (int kb = 0; kb < 4; ++kb)
      Areg[m][kb] = Areg[m][kb] * (_Float16)SCALE2;

  const char* Bbase = Hb + (size_t)cg * 65536;     // cg*16 colblks * 4096B

#define BLOAD(T, NI, KB) \
  (*(const f16x8*)(Bbase + ((T) * 4 + (NI)) * 4096 + (KB) * 1024 + laneoff))

  f32x4 acc[2][4];
  float mxv[2] = {-3.0e38f, -3.0e38f}, sv[2] = {0.0f, 0.0f};

  f16x8 Bb[2][4];
#pragma unroll
  for (int ni = 0; ni < 4; ++ni) Bb[0][ni] = BLOAD(0, ni, 0);

#pragma unroll
  for (int t = 0; t < 4; ++t) {
#pragma unroll
    for (int m = 0; m < 2; ++m)
#pragma unroll
      for (int ni = 0; ni < 4; ++ni) acc[m][ni] = f32x4{0.f, 0.f, 0.f, 0.f};
    uint32_t labw[4];
#pragma unroll
    for (int ni = 0; ni < 4; ++ni)
      labw[ni] = *(const uint32_t*)(lab8 + cg * 256 + t * 64 + ni * 16 + lq * 4);

#pragma unroll
    for (int kb = 0; kb < 4; ++kb) {
      int cur = kb & 1;
      if (kb < 3) {
#pragma unroll
        for (int ni = 0; ni < 4; ++ni) Bb[cur ^ 1][ni] = BLOAD(t, ni, kb + 1);
      } else if (t < 3) {
#pragma unroll
        for (int ni = 0; ni < 4; ++ni) Bb[cur ^ 1][ni] = BLOAD(t + 1, ni, 0);
      }
      __builtin_amdgcn_s_setprio(1);
#pragma unroll
      for (int m = 0; m < 2; ++m)
#pragma unroll
        for (int ni = 0; ni < 4; ++ni)
          acc[m][ni] = __builtin_amdgcn_mfma_f32_16x16x32_f16(Bb[cur][ni], Areg[m][kb], acc[m][ni], 0, 0, 0);
      __builtin_amdgcn_s_setprio(0);
    }

    // ---- per-lane epilogue: mask in place, lane-local online (max, exp2-sum) ----
#pragma unroll
    for (int m = 0; m < 2; ++m) {
#pragma unroll
      for (int ni = 0; ni < 4; ++ni)
#pragma unroll
        for (int r = 0; r < 4; ++r) {
          int lc = (labw[ni] >> (8 * r)) & 255;
          acc[m][ni][r] = (lrw[m] != lc) ? acc[m][ni][r] : 0.0f;
        }
      float b0 = fmaxf(fmaxf(acc[m][0][0], acc[m][0][1]), fmaxf(acc[m][0][2], acc[m][0][3]));
      float b1 = fmaxf(fmaxf(acc[m][1][0], acc[m][1][1]), fmaxf(acc[m][1][2], acc[m][1][3]));
      float b2 = fmaxf(fmaxf(acc[m][2][0], acc[m][2][1]), fmaxf(acc[m][2][2], acc[m][2][3]));
      float b3 = fmaxf(fmaxf(acc[m][3][0], acc[m][3][1]), fmaxf(acc[m][3][2], acc[m][3][3]));
      float bm = fmaxf(fmaxf(b0, b1), fmaxf(b2, b3));
      float nm = fmaxf(mxv[m], bm);
      float s0 = 0.f, s1 = 0.f, s2 = 0.f, s3 = 0.f;
#pragma unroll
      for (int r = 0; r < 4; ++r) {
        s0 += EXP2(acc[m][0][r] - nm);
        s1 += EXP2(acc[m][1][r] - nm);
        s2 += EXP2(acc[m][2][r] - nm);
        s3 += EXP2(acc[m][3][r] - nm);
      }
      sv[m] = sv[m] * EXP2(mxv[m] - nm) + ((s0 + s1) + (s2 + s3));
      mxv[m] = nm;
    }
  }
#undef BLOAD

  // ---- merge (M,S) across the 4 lq lane-groups (exact max-merge), write partials ----
#pragma unroll
  for (int m = 0; m < 2; ++m) {
    float M = mxv[m], S = sv[m];
#pragma unroll
    for (int off = 16; off < 64; off <<= 1) {
      float Mo = __shfl_xor(M, off, 64);
      float So = __shfl_xor(S, off, 64);
      float Mn = fmaxf(M, Mo);
      S = S * EXP2(M - Mn) + So * EXP2(Mo - Mn);
      M = Mn;
    }
    if (lane < 16) {
      pM[(size_t)cg * N_TOT + rowbase + m * 16 + lane] = M;
      pS[(size_t)cg * N_TOT + rowbase + m * 16 + lane] = S;
    }
  }
}

// ---------------- combine 32 chunk-partials per row, partial-sum S per block ----------------
__global__ __launch_bounds__(256) void rowred13_kernel(const float* __restrict__ pM,
                                                       const float* __restrict__ pS,
                                                       float* __restrict__ blockS) {
  int row = blockIdx.x * 256 + threadIdx.x;   // 32 blocks x 256 = 8192 rows
  float M = -3.0e38f;
#pragma unroll
  for (int c = 0; c < NCH; ++c) M = fmaxf(M, pM[(size_t)c * N_TOT + row]);
  float s = 0.0f;
#pragma unroll
  for (int c = 0; c < NCH; ++c)
    s += pS[(size_t)c * N_TOT + row] * EXP2(pM[(size_t)c * N_TOT + row] - M);
  __shared__ float red[256];
  red[threadIdx.x] = s;
  __syncthreads();
  for (int st = 128; st > 0; st >>= 1) {
    if (threadIdx.x < st) red[threadIdx.x] += red[threadIdx.x + st];
    __syncthreads();
  }
  if (threadIdx.x == 0) blockS[blockIdx.x] = red[0];
}

// ---------------- final scalar: S, N, validity -> loss ----------------
__global__ void final13_kernel(const float* __restrict__ blockS, const int* __restrict__ cnt,
                               float* __restrict__ out) {
  int lane = threadIdx.x;              // 1 wave
  float s = (lane < 32) ? blockS[lane] : 0.0f;
#pragma unroll
  for (int off = 1; off < 64; off <<= 1) s += __shfl_xor(s, off, 64);
  if (lane == 0) {
    double Stot = (double)s;
    long long sumsq = 0;
    int nval = 0;
    for (int c = 0; c < 128; ++c) {
      long long cc = cnt[c];
      sumsq += cc * cc;
      if (cc > 0 && cc < BSZ) nval += 2 * (int)cc;   // valid rows iff not all labels equal
    }
    double Nd = (double)N_TOT * (double)N_TOT - 4.0 * (double)sumsq;
    float loss;
    if (Nd <= 0.0 || nval == 0) {
      loss = logf(1e-6f);              // all_zero branch: xv stays 0 -> log(eps)
    } else {
      float x = (float)(Stot / Nd);
      loss = ((float)nval * logf(x + 1e-6f) +
              (float)(N_TOT - nval) * logf(1e-6f)) / (float)N_TOT;
    }
    out[0] = loss;
  }
}

extern "C" void kernel_launch(void* const* d_in, const int* in_sizes, int n_in,
                              void* d_out, int out_size, void* d_ws, size_t ws_size,
                              hipStream_t stream) {
  const float* feat = (const float*)d_in[0];
  const int* labels = (const int*)d_in[1];
  float* out = (float*)d_out;

  char* ws = (char*)d_ws;
  _Float16* H2        = (_Float16*)(ws);                 // 8192*128*2 = 2,097,152 (tiled layout)
  unsigned char* lab8 = (unsigned char*)(ws + 2097152);  // 8,192
  float* pM           = (float*)(ws + 2105344);          // 32*8192*4 = 1,048,576
  float* pS           = (float*)(ws + 3153920);          // 1,048,576
  int* cnt            = (int*)(ws + 4202496);            // 512
  float* blockS       = (float*)(ws + 4203008);          // 128

  prep13_kernel<<<513, 256, 0, stream>>>(feat, labels, H2, lab8, cnt);
  gemm13_kernel<<<2048, 256, 0, stream>>>(H2, labels, lab8, pM, pS);
  rowred13_kernel<<<32, 256, 0, stream>>>(pM, pS, blockS);
  final13_kernel<<<1, 64, 0, stream>>>(blockS, cnt, out);
}

// Round 14
// 46.071 us; speedup vs baseline: 1.4669x; 1.0957x over previous
//
#include <hip/hip_runtime.h>
#include <hip/hip_bf16.h>
#include <stdint.h>

#define N_TOT 8192
#define BSZ   4096
#define NCH   32                     // 8192/256 column groups
#define SQS   5.3715827f             // sqrt(20*log2(e)): folded into H2; products scaled 20*log2(e)

typedef _Float16 f16x8 __attribute__((ext_vector_type(8)));
typedef float f32x4 __attribute__((ext_vector_type(4)));

// Native 2^x that ALWAYS inlines (no call ABI, no scratch):
__device__ __forceinline__ float fast_exp2(float x) {
#if __has_builtin(__builtin_amdgcn_exp2f)
  return __builtin_amdgcn_exp2f(x);     // bare v_exp_f32
#else
  return exp2f(x);                      // header-inline libm (no extern call)
#endif
}
#define EXP2(x) fast_exp2(x)

// ---------------- prep: f32 -> fp16*sqrt(SCALE2) in FRAGMENT-TILE layout ----------------
// H2 byte addr = rowblk*4096 + k8*256 + (r&15)*16  (rowblk=r>>4, k8=k/8)
// => every MFMA fragment (16 rows x 8 k) is one contiguous 1KB wave load.
__global__ __launch_bounds__(256) void prep14_kernel(
    const float* __restrict__ feat, const int* __restrict__ labels,
    _Float16* __restrict__ H2, unsigned char* __restrict__ lab8, int* __restrict__ cnt) {
  if (blockIdx.x == 512) {   // label histogram + byte labels
    __shared__ int h[128];
    if (threadIdx.x < 128) h[threadIdx.x] = 0;
    __syncthreads();
    for (int i = threadIdx.x; i < BSZ; i += 256) atomicAdd(&h[labels[i] & 127], 1);
    __syncthreads();
    if (threadIdx.x < 128) cnt[threadIdx.x] = h[threadIdx.x];
    for (int i = threadIdx.x; i < N_TOT; i += 256)
      lab8[i] = (unsigned char)labels[i & (BSZ - 1)];
    return;
  }
  int idx = blockIdx.x * 256 + threadIdx.x;   // 131072
  int rowblk = idx >> 8, inner = idx & 255;
  int k8 = inner >> 4, rlo = inner & 15;
  int r = rowblk * 16 + rlo;
  int b = r & (BSZ - 1), v = r >> 12;         // cf row r = features[b, v, :]
  const float* src = feat + ((size_t)((b << 1) + v) << 7) + k8 * 8;
  float4 x0 = *(const float4*)src;
  float4 x1 = *(const float4*)(src + 4);
  float xs[8] = {x0.x, x0.y, x0.z, x0.w, x1.x, x1.y, x1.z, x1.w};
  f16x8 hv;
#pragma unroll
  for (int jj = 0; jj < 8; ++jj) hv[jj] = (_Float16)(xs[jj] * SQS);
  *(f16x8*)((char*)H2 + (size_t)idx * 16) = hv;
}

// ---------------- LDS-shared strip GEMM: block = 128 rows x 256 cols, K=128 ----------------
// 4 waves x 32 rows; B tile (64 cols x 128 k = 16KB) staged ONCE per block into LDS
// (global_load_lds, linear dest, fragment-tile source => conflict-free lane*16B reads),
// double-buffered with counted vmcnt + raw barriers. A frags global->VGPR per wave.
// Transposed MFMA: acc[m][ni][r] = C[row=rowbase+m*16+lr16][col=cg*256+t*64+ni*16+lq*4+r]
// Per-lane online (max, exp2-sum); lq-merged at the end.
__global__ __launch_bounds__(256) void gemm14_kernel(
    const _Float16* __restrict__ H2, const int* __restrict__ labels,
    const unsigned char* __restrict__ lab8,
    float* __restrict__ pM, float* __restrict__ pS) {
  __shared__ __align__(16) char ldsB[2][16384];

  int orig = blockIdx.x;                 // 2048 blocks
  int xcd = orig & 7, j = orig >> 3;     // dispatch round-robins XCDs (perf-only)
  int cg = xcd * 4 + (j & 3);            // [0,32): 4 col-groups pinned per XCD
  int rg = j >> 2;                       // [0,64): 128-row group
  int wave = threadIdx.x >> 6, lane = threadIdx.x & 63;
  int lq = lane >> 4, lr16 = lane & 15;

  const uint32_t rowbase = (uint32_t)rg * 128 + wave * 32;
  const char* Hb = (const char*)H2;
  const uint32_t laneoff = lq * 256 + lr16 * 16;   // byte offset within a 1KB fragment

  int lrw[2];
#pragma unroll
  for (int m = 0; m < 2; ++m)
    lrw[m] = labels[(rowbase + m * 16 + lr16) & (BSZ - 1)];

  // ---- A fragments (8 coalesced 1KB loads); scale pre-folded into H2 ----
  f16x8 Areg[2][4];
#pragma unroll
  for (int m = 0; m < 2; ++m)
#pragma unroll
    for (int kb = 0; kb < 4; ++kb)
      Areg[m][kb] = *(const f16x8*)(Hb + (size_t)((rowbase >> 4) + m) * 4096 + kb * 1024 + laneoff);

  const char* Bsrc = Hb + (size_t)cg * 65536;      // cg's 16 colblks * 4096B

  // stage: 16 x 1KB chunks per tile; wave w carries chunks w*4..w*4+3 (chunk = ni*4+kb)
#define STAGE(T, BUF)                                                                     \
  {                                                                                       \
    _Pragma("unroll")                                                                     \
    for (int i = 0; i < 4; ++i) {                                                         \
      int chunk = wave * 4 + i;                                                           \
      __builtin_amdgcn_global_load_lds(                                                   \
          (const __attribute__((address_space(1))) void*)(Bsrc + ((T) * 4 + (chunk >> 2)) * 4096 + (chunk & 3) * 1024 + lane * 16), \
          (__attribute__((address_space(3))) void*)(&ldsB[BUF][chunk * 1024]), 16, 0, 0); \
    }                                                                                     \
  }

  STAGE(0, 0);
  asm volatile("s_waitcnt vmcnt(0)" ::: "memory");   // tile 0 (and nothing else LDS-bound) landed
  __builtin_amdgcn_sched_barrier(0);
  __builtin_amdgcn_s_barrier();

  f32x4 acc[2][4];
  float mxv[2] = {-3.0e38f, -3.0e38f}, sv[2] = {0.0f, 0.0f};

#pragma unroll
  for (int t = 0; t < 4; ++t) {
    if (t < 3) STAGE(t + 1, (t + 1) & 1);            // prefetch next tile into other buf
    const char* Bb = ldsB[t & 1];

#pragma unroll
    for (int m = 0; m < 2; ++m)
#pragma unroll
      for (int ni = 0; ni < 4; ++ni) acc[m][ni] = f32x4{0.f, 0.f, 0.f, 0.f};

    // ---- MFMA with per-kb double-buffered fragment reads from LDS ----
    f16x8 Bf[2][4];
#pragma unroll
    for (int ni = 0; ni < 4; ++ni)
      Bf[0][ni] = *(const f16x8*)(Bb + ni * 4096 + laneoff);
#pragma unroll
    for (int kb = 0; kb < 4; ++kb) {
      int cur = kb & 1;
      if (kb < 3) {
#pragma unroll
        for (int ni = 0; ni < 4; ++ni)
          Bf[cur ^ 1][ni] = *(const f16x8*)(Bb + ni * 4096 + (kb + 1) * 1024 + laneoff);
      }
      __builtin_amdgcn_s_setprio(1);
#pragma unroll
      for (int m = 0; m < 2; ++m)
#pragma unroll
        for (int ni = 0; ni < 4; ++ni)
          acc[m][ni] = __builtin_amdgcn_mfma_f32_16x16x32_f16(Bf[cur][ni], Areg[m][kb], acc[m][ni], 0, 0, 0);
      __builtin_amdgcn_s_setprio(0);
    }

    // ---- epilogue: shared label bytes, per-lane online (max, exp2-sum) ----
    uint32_t labw[4];
#pragma unroll
    for (int ni = 0; ni < 4; ++ni)
      labw[ni] = *(const uint32_t*)(lab8 + cg * 256 + t * 64 + ni * 16 + lq * 4);
    int lc[16];
#pragma unroll
    for (int i = 0; i < 16; ++i) lc[i] = (labw[i >> 2] >> (8 * (i & 3))) & 255;

#pragma unroll
    for (int m = 0; m < 2; ++m) {
      float v[16];
#pragma unroll
      for (int ni = 0; ni < 4; ++ni)
#pragma unroll
        for (int r = 0; r < 4; ++r)
          v[ni * 4 + r] = (lrw[m] != lc[ni * 4 + r]) ? acc[m][ni][r] : 0.0f;
      float m01 = fmaxf(v[0], v[1]),  m23 = fmaxf(v[2], v[3]);
      float m45 = fmaxf(v[4], v[5]),  m67 = fmaxf(v[6], v[7]);
      float m89 = fmaxf(v[8], v[9]),  mab = fmaxf(v[10], v[11]);
      float mcd = fmaxf(v[12], v[13]), mef = fmaxf(v[14], v[15]);
      float bm = fmaxf(fmaxf(fmaxf(m01, m23), fmaxf(m45, m67)),
                       fmaxf(fmaxf(m89, mab), fmaxf(mcd, mef)));
      float nm = fmaxf(mxv[m], bm);
      float s0 = 0.f, s1 = 0.f, s2 = 0.f, s3 = 0.f;
#pragma unroll
      for (int r = 0; r < 4; ++r) {
        s0 += EXP2(v[r] - nm);
        s1 += EXP2(v[4 + r] - nm);
        s2 += EXP2(v[8 + r] - nm);
        s3 += EXP2(v[12 + r] - nm);
      }
      sv[m] = sv[m] * EXP2(mxv[m] - nm) + ((s0 + s1) + (s2 + s3));
      mxv[m] = nm;
    }

    // drain this wave's prefetch DMAs, then publish/protect buffers
    asm volatile("s_waitcnt vmcnt(0)" ::: "memory");
    __builtin_amdgcn_sched_barrier(0);
    __builtin_amdgcn_s_barrier();
  }
#undef STAGE

  // ---- merge (M,S) across the 4 lq lane-groups (exact max-merge), write partials ----
#pragma unroll
  for (int m = 0; m < 2; ++m) {
    float M = mxv[m], S = sv[m];
#pragma unroll
    for (int off = 16; off < 64; off <<= 1) {
      float Mo = __shfl_xor(M, off, 64);
      float So = __shfl_xor(S, off, 64);
      float Mn = fmaxf(M, Mo);
      S = S * EXP2(M - Mn) + So * EXP2(Mo - Mn);
      M = Mn;
    }
    if (lane < 16) {
      pM[(size_t)cg * N_TOT + rowbase + m * 16 + lane] = M;
      pS[(size_t)cg * N_TOT + rowbase + m * 16 + lane] = S;
    }
  }
}

// ---------------- combine 32 chunk-partials per row, partial-sum S per block ----------------
__global__ __launch_bounds__(256) void rowred14_kernel(const float* __restrict__ pM,
                                                       const float* __restrict__ pS,
                                                       float* __restrict__ blockS) {
  int row = blockIdx.x * 256 + threadIdx.x;   // 32 blocks x 256 = 8192 rows
  float M = -3.0e38f;
#pragma unroll
  for (int c = 0; c < NCH; ++c) M = fmaxf(M, pM[(size_t)c * N_TOT + row]);
  float s = 0.0f;
#pragma unroll
  for (int c = 0; c < NCH; ++c)
    s += pS[(size_t)c * N_TOT + row] * EXP2(pM[(size_t)c * N_TOT + row] - M);
  __shared__ float red[256];
  red[threadIdx.x] = s;
  __syncthreads();
  for (int st = 128; st > 0; st >>= 1) {
    if (threadIdx.x < st) red[threadIdx.x] += red[threadIdx.x + st];
    __syncthreads();
  }
  if (threadIdx.x == 0) blockS[blockIdx.x] = red[0];
}

// ---------------- final scalar: S, N, validity -> loss ----------------
__global__ void final14_kernel(const float* __restrict__ blockS, const int* __restrict__ cnt,
                               float* __restrict__ out) {
  int lane = threadIdx.x;              // 1 wave
  float s = (lane < 32) ? blockS[lane] : 0.0f;
#pragma unroll
  for (int off = 1; off < 64; off <<= 1) s += __shfl_xor(s, off, 64);
  if (lane == 0) {
    double Stot = (double)s;
    long long sumsq = 0;
    int nval = 0;
    for (int c = 0; c < 128; ++c) {
      long long cc = cnt[c];
      sumsq += cc * cc;
      if (cc > 0 && cc < BSZ) nval += 2 * (int)cc;   // valid rows iff not all labels equal
    }
    double Nd = (double)N_TOT * (double)N_TOT - 4.0 * (double)sumsq;
    float loss;
    if (Nd <= 0.0 || nval == 0) {
      loss = logf(1e-6f);              // all_zero branch: xv stays 0 -> log(eps)
    } else {
      float x = (float)(Stot / Nd);
      loss = ((float)nval * logf(x + 1e-6f) +
              (float)(N_TOT - nval) * logf(1e-6f)) / (float)N_TOT;
    }
    out[0] = loss;
  }
}

extern "C" void kernel_launch(void* const* d_in, const int* in_sizes, int n_in,
                              void* d_out, int out_size, void* d_ws, size_t ws_size,
                              hipStream_t stream) {
  const float* feat = (const float*)d_in[0];
  const int* labels = (const int*)d_in[1];
  float* out = (float*)d_out;

  char* ws = (char*)d_ws;
  _Float16* H2        = (_Float16*)(ws);                 // 8192*128*2 = 2,097,152 (tiled layout)
  unsigned char* lab8 = (unsigned char*)(ws + 2097152);  // 8,192
  float* pM           = (float*)(ws + 2105344);          // 32*8192*4 = 1,048,576
  float* pS           = (float*)(ws + 3153920);          // 1,048,576
  int* cnt            = (int*)(ws + 4202496);            // 512
  float* blockS       = (float*)(ws + 4203008);          // 128

  prep14_kernel<<<513, 256, 0, stream>>>(feat, labels, H2, lab8, cnt);
  gemm14_kernel<<<2048, 256, 0, stream>>>(H2, labels, lab8, pM, pS);
  rowred14_kernel<<<32, 256, 0, stream>>>(pM, pS, blockS);
  final14_kernel<<<1, 64, 0, stream>>>(blockS, cnt, out);
}